// Round 10
// baseline (6833.270 us; speedup 1.0000x reference)
//
#include <hip/hip_runtime.h>
#include <cmath>

// ---------------------------------------------------------------------------
// BertBiLSTMCRF round 10 = round 9 resubmitted verbatim (round 9 hit
// GPUAcquisitionTimeout - kernel never ran). Software-pipelined exchange:
// 32 blocks x 512 threads; block m owns units [8m,8m+8) both dirs.
// Per step: A: all F-partials | B: U(tid<256) F-update/publish/flagF  while
// R(tid>=256) pollB(s-1)+readback hS_B | C: all B-partials | D: U B-update/
// publish/flagB while R pollF(s)+readback hS_F.  Flags are per-wave (4 per
// block/dir) with release stores; polls see flags aged by a full compute
// phase. Parity double-buffered hG; race-free: consumer readback loads drain
// at BAR4 (wave vmcnt) -> next flag store is program-after -> producer's poll
// observing that flag happens-after the reads -> overwrite one step later is
// safe. Pure fp32 numerics (validated r2-r8).
// ---------------------------------------------------------------------------

#define NB 32
#define NT 512
#define ND 768
#define NH 256
#define NG 1024   // 4*NH
#define NC 2048   // 2*NG
#define NL 9
#define NHC 512   // 2*NH
#define PPD 32    // participating blocks
#define HPAD 260  // padded row stride for hS rows
#define HSZ  (32 * HPAD)
#define NBUF (2 * NB * NH)   // one parity buffer: [2 dirs][32 m][32 b][8 u]

typedef float f32x4 __attribute__((ext_vector_type(4)));

static const size_t OFF_WIHT  = 0;                       // 1572864 floats
static const size_t OFF_WHHT  = 1572864;                 // 524288
static const size_t OFF_XPART = 2097152;                 // 33554432
static const size_t OFF_HCAT  = 35651584;                // 8388608
static const size_t OFF_HG    = 44040192;                // 32768
static const size_t OFF_CTR   = 44072960;                // 1024 ints (flags)

// ---------------------------------------------------------------- prep ------
__global__ void prep(const float* __restrict__ wihf, const float* __restrict__ wihb,
                     const float* __restrict__ whhf, const float* __restrict__ whhb,
                     float* __restrict__ w_ihT, float* __restrict__ w_hhT,
                     float* __restrict__ d_loss, int* __restrict__ flags) {
  int idx = blockIdx.x * 256 + threadIdx.x;
  if (idx == 0) d_loss[0] = 0.f;
  if (idx < 1024) flags[idx] = 0;        // [dir][m][wave] step flags (256 used)
  if (idx < 1572864) {
    int k = idx >> 11;
    int c = idx & 2047;
    int d = c >> 10;
    int j = c & 1023;
    w_ihT[idx] = d ? wihb[j * ND + k] : wihf[j * ND + k];
  } else {
    int i2 = idx - 1572864;
    int d = i2 >> 18;
    int r = i2 & 262143;
    int k = r >> 10;
    int j = r & 1023;
    w_hhT[i2] = d ? whhb[j * NH + k] : whhf[j * NH + k];
  }
}

// -------------------------------------------------------------- gemm_x ------
__global__ __launch_bounds__(256, 2)
void gemm_x(const float* __restrict__ x, const float* __restrict__ wT,
            const float* __restrict__ bf, const float* __restrict__ bb,
            float* __restrict__ xpart) {
  __shared__ float As[8][128];
  __shared__ float Bs[8][128];
  const int tid = threadIdx.x;
  const int tx = tid & 15, ty = tid >> 4;
  const int r0 = blockIdx.y * 128, c0 = blockIdx.x * 128;

  float acc[8][8] = {};

  const int arow = tid >> 1;
  const int akq  = (tid & 1) * 4;
  const int rA = r0 + arow;
  const float* aptr = x + ((size_t)((rA & 31) * NT + (rA >> 5)) * ND) + akq;
  const int bk = tid >> 5;
  const int bc = (tid & 31) * 4;
  const float* bptr = wT + (size_t)bk * NC + c0 + bc;

  for (int k0 = 0; k0 < ND; k0 += 8) {
    float4 av = *(const float4*)(aptr + k0);
    float4 bv = *(const float4*)(bptr + (size_t)k0 * NC);
    __syncthreads();
    As[akq + 0][arow] = av.x;
    As[akq + 1][arow] = av.y;
    As[akq + 2][arow] = av.z;
    As[akq + 3][arow] = av.w;
    *(float4*)&Bs[bk][bc] = bv;
    __syncthreads();
#pragma unroll
    for (int k = 0; k < 8; ++k) {
      float4 a0 = *(const float4*)&As[k][ty * 8];
      float4 a1 = *(const float4*)&As[k][ty * 8 + 4];
      float4 b0 = *(const float4*)&Bs[k][tx * 8];
      float4 b1 = *(const float4*)&Bs[k][tx * 8 + 4];
      float am[8] = {a0.x, a0.y, a0.z, a0.w, a1.x, a1.y, a1.z, a1.w};
      float bm[8] = {b0.x, b0.y, b0.z, b0.w, b1.x, b1.y, b1.z, b1.w};
#pragma unroll
      for (int i = 0; i < 8; ++i)
#pragma unroll
        for (int j = 0; j < 8; ++j) acc[i][j] += am[i] * bm[j];
    }
  }

  const int cbase = c0 + tx * 8;
  float bias[8];
#pragma unroll
  for (int j = 0; j < 8; ++j) {
    int c = cbase + j;
    bias[j] = (c < NG) ? bf[c] : bb[c - NG];
  }
#pragma unroll
  for (int i = 0; i < 8; ++i) {
    int r = r0 + ty * 8 + i;
    float4 v0 = {acc[i][0] + bias[0], acc[i][1] + bias[1],
                 acc[i][2] + bias[2], acc[i][3] + bias[3]};
    float4 v1 = {acc[i][4] + bias[4], acc[i][5] + bias[5],
                 acc[i][6] + bias[6], acc[i][7] + bias[7]};
    *(float4*)(xpart + (size_t)r * NC + cbase) = v0;
    *(float4*)(xpart + (size_t)r * NC + cbase + 4) = v1;
  }
}

// ------------------------------------------------------------ lstm_scan -----
__global__ __launch_bounds__(512, 1)
void lstm_scan(const float* __restrict__ whhT, const float* __restrict__ xpart,
               float* __restrict__ hcat, float* __restrict__ hG,
               int* __restrict__ flags) {
  __shared__ float wS[2 * 256 * 32];   // [d][k][l] 64KB
  __shared__ float hS[2 * HSZ];        // [d][b][k] padded, 65KB
  __shared__ float pSwF[32 * 68];      // partials F, 8.5KB
  __shared__ float pSwB[32 * 68];      // partials B, 8.5KB
  const int tid = threadIdx.x;
  const int m = blockIdx.x;

  // one-time weight load
  for (int dd = 0; dd < 2; ++dd) {
    const float* wsrc = whhT + (size_t)dd * NH * NG;
    for (int it = 0; it < 16; ++it) {
      int i = it * 512 + tid;
      int k = i >> 5, l = i & 31;
      int g = l >> 3, u2 = l & 7;
      wS[(dd * 256 + k) * 32 + l] = wsrc[(size_t)k * NG + g * 256 + m * 8 + u2];
    }
  }
  for (int i = tid; i < 2 * HSZ; i += 512) hS[i] = 0.f;
  __syncthreads();

  // roles
  const int kh = tid >> 8;             // 0 (U) / 1 (R) : k-half for partials
  const int pr = tid & 255;
  const int pb = pr >> 3;
  const int pcg = pr & 7;
  const int l0 = pcg * 4;
  const int ub = tid >> 3;             // update batch (U only)
  const int uu = tid & 7;              // update unit (U only)
  const int c0i = (uu >> 2) * 8 + (uu & 3);
  const int lane = tid & 63;
  const int uwave = tid >> 6;          // 0..3 for U waves

  float cf = 0.f, cb = 0.f;

  // flag layout: F: flags[0..127] = [m][wave]; B: flags[128..255]
  int* flF = flags;
  int* flB = flags + 128;

  for (int s = 0; s < NT; ++s) {
    const int tf = s, tb = NT - 1 - s;

    // x-part prefetch (U threads)
    float xf[4], xb[4];
    if (tid < 256) {
      const float* xpf = xpart + ((size_t)(tf * NB + ub) * NC) + m * 8 + uu;
      const float* xpb = xpart + ((size_t)(tb * NB + ub) * NC) + NG + m * 8 + uu;
#pragma unroll
      for (int g = 0; g < 4; ++g) { xf[g] = xpf[g * 256]; xb[g] = xpb[g * 256]; }
    }

    // ---- A: F-partials (all threads, k-split) ----
    {
      const float* hrow = hS + pb * HPAD + kh * 128;
      const float* wcol = wS + (size_t)(kh * 128) * 32 + l0;
      f32x4 acc = {0.f, 0.f, 0.f, 0.f};
#pragma unroll 4
      for (int kk = 0; kk < 128; kk += 4) {
        f32x4 hv = *(const f32x4*)(hrow + kk);
        f32x4 w0 = *(const f32x4*)(wcol + (size_t)(kk + 0) * 32);
        f32x4 w1 = *(const f32x4*)(wcol + (size_t)(kk + 1) * 32);
        f32x4 w2 = *(const f32x4*)(wcol + (size_t)(kk + 2) * 32);
        f32x4 w3 = *(const f32x4*)(wcol + (size_t)(kk + 3) * 32);
        acc += hv.x * w0; acc += hv.y * w1; acc += hv.z * w2; acc += hv.w * w3;
      }
      *(f32x4*)(pSwF + pb * 68 + (pcg * 2 + kh) * 4) = acc;
    }
    __syncthreads();                                   // BAR1

    // ---- B: U = F-update/publish/flagF  ||  R = pollB(s-1)+readback hS_B ----
    if (tid < 256) {
      const float* pS = pSwF + ub * 68;
      float g0 = pS[c0i]      + pS[c0i + 4]  + xf[0];
      float g1 = pS[c0i + 16] + pS[c0i + 20] + xf[1];
      float g2 = pS[c0i + 32] + pS[c0i + 36] + xf[2];
      float g3 = pS[c0i + 48] + pS[c0i + 52] + xf[3];
      float ii = 1.f / (1.f + expf(-g0));
      float ff = 1.f / (1.f + expf(-g1));
      float tg = tanhf(g2);
      float oo = 1.f / (1.f + expf(-g3));
      cf = ff * cf + ii * tg;
      float h = oo * tanhf(cf);
      hcat[((size_t)(ub * NT + tf)) * NHC + m * 8 + uu] = h;
      float* dst = hG + ((s & 1) ? NBUF : 0) + m * 256 + ub * 8 + uu;
      __hip_atomic_store(dst, h, __ATOMIC_RELAXED, __HIP_MEMORY_SCOPE_AGENT);
      if (lane == 0)   // release: orders this wave's publishes (vmcnt drain)
        __hip_atomic_store(&flF[m * 4 + uwave], s + 1, __ATOMIC_RELEASE,
                           __HIP_MEMORY_SCOPE_AGENT);
    } else if (s > 0) {
      // poll flagsB >= s (set at step s-1), aged ~1 full iteration
      {
        const long long* fl2 = (const long long*)flB;
        long long t0 = wall_clock64();
        for (;;) {
          long long v = __hip_atomic_load(&fl2[lane], __ATOMIC_RELAXED,
                                          __HIP_MEMORY_SCOPE_AGENT);
          int lo = (int)v, hi = (int)(v >> 32);
          if (__ballot(lo >= s && hi >= s) == ~0ULL) break;
          if (wall_clock64() - t0 > 200000LL) break;   // ~2ms hang guard
        }
      }
      // readback hB(s-1) -> hS_B : 16x 8B bypass loads (R threads only)
      const unsigned long long* src = (const unsigned long long*)
          (hG + (((s - 1) & 1) ? NBUF : 0) + 8192);
      unsigned long long vv[16];
#pragma unroll
      for (int i = 0; i < 16; ++i)
        vv[i] = __hip_atomic_load(&src[i * 256 + (tid - 256)], __ATOMIC_RELAXED,
                                  __HIP_MEMORY_SCOPE_AGENT);
      float* hd = hS + HSZ;
#pragma unroll
      for (int i = 0; i < 16; ++i) {
        int f = i * 256 + (tid - 256);
        union { unsigned long long uu; float ff2[2]; } cv;
        cv.uu = vv[i];
        int mq = f >> 7, r = f & 127, bb = r >> 2, u2 = (r & 3) * 2;
        hd[bb * HPAD + mq * 8 + u2] = cv.ff2[0];
        hd[bb * HPAD + mq * 8 + u2 + 1] = cv.ff2[1];
      }
    }
    __syncthreads();                                   // BAR2

    // ---- C: B-partials (all threads, k-split) ----
    {
      const float* hrow = hS + HSZ + pb * HPAD + kh * 128;
      const float* wcol = wS + (size_t)(256 + kh * 128) * 32 + l0;
      f32x4 acc = {0.f, 0.f, 0.f, 0.f};
#pragma unroll 4
      for (int kk = 0; kk < 128; kk += 4) {
        f32x4 hv = *(const f32x4*)(hrow + kk);
        f32x4 w0 = *(const f32x4*)(wcol + (size_t)(kk + 0) * 32);
        f32x4 w1 = *(const f32x4*)(wcol + (size_t)(kk + 1) * 32);
        f32x4 w2 = *(const f32x4*)(wcol + (size_t)(kk + 2) * 32);
        f32x4 w3 = *(const f32x4*)(wcol + (size_t)(kk + 3) * 32);
        acc += hv.x * w0; acc += hv.y * w1; acc += hv.z * w2; acc += hv.w * w3;
      }
      *(f32x4*)(pSwB + pb * 68 + (pcg * 2 + kh) * 4) = acc;
    }
    __syncthreads();                                   // BAR3

    // ---- D: U = B-update/publish/flagB  ||  R = pollF(s)+readback hS_F ----
    if (tid < 256) {
      const float* pS = pSwB + ub * 68;
      float g0 = pS[c0i]      + pS[c0i + 4]  + xb[0];
      float g1 = pS[c0i + 16] + pS[c0i + 20] + xb[1];
      float g2 = pS[c0i + 32] + pS[c0i + 36] + xb[2];
      float g3 = pS[c0i + 48] + pS[c0i + 52] + xb[3];
      float ii = 1.f / (1.f + expf(-g0));
      float ff = 1.f / (1.f + expf(-g1));
      float tg = tanhf(g2);
      float oo = 1.f / (1.f + expf(-g3));
      cb = ff * cb + ii * tg;
      float h = oo * tanhf(cb);
      hcat[((size_t)(ub * NT + tb)) * NHC + NH + m * 8 + uu] = h;
      float* dst = hG + ((s & 1) ? NBUF : 0) + 8192 + m * 256 + ub * 8 + uu;
      __hip_atomic_store(dst, h, __ATOMIC_RELAXED, __HIP_MEMORY_SCOPE_AGENT);
      if (lane == 0)
        __hip_atomic_store(&flB[m * 4 + uwave], s + 1, __ATOMIC_RELEASE,
                           __HIP_MEMORY_SCOPE_AGENT);
    } else if (s < NT - 1) {
      // poll flagsF >= s+1 (set in phase B this iteration, aged by C)
      {
        const long long* fl2 = (const long long*)flF;
        long long t0 = wall_clock64();
        for (;;) {
          long long v = __hip_atomic_load(&fl2[lane], __ATOMIC_RELAXED,
                                          __HIP_MEMORY_SCOPE_AGENT);
          int lo = (int)v, hi = (int)(v >> 32);
          if (__ballot(lo >= s + 1 && hi >= s + 1) == ~0ULL) break;
          if (wall_clock64() - t0 > 200000LL) break;   // ~2ms hang guard
        }
      }
      // readback hF(s) -> hS_F
      const unsigned long long* src = (const unsigned long long*)
          (hG + ((s & 1) ? NBUF : 0));
      unsigned long long vv[16];
#pragma unroll
      for (int i = 0; i < 16; ++i)
        vv[i] = __hip_atomic_load(&src[i * 256 + (tid - 256)], __ATOMIC_RELAXED,
                                  __HIP_MEMORY_SCOPE_AGENT);
      float* hd = hS;
#pragma unroll
      for (int i = 0; i < 16; ++i) {
        int f = i * 256 + (tid - 256);
        union { unsigned long long uu; float ff2[2]; } cv;
        cv.uu = vv[i];
        int mq = f >> 7, r = f & 127, bb = r >> 2, u2 = (r & 3) * 2;
        hd[bb * HPAD + mq * 8 + u2] = cv.ff2[0];
        hd[bb * HPAD + mq * 8 + u2 + 1] = cv.ff2[1];
      }
    }
    __syncthreads();                                   // BAR4
  }
}

// ------------------------------------------------------------ emissions -----
__global__ void emissions(const float* __restrict__ hcat, const float* __restrict__ wtag,
                          const float* __restrict__ btag, float* __restrict__ em) {
  __shared__ float wS[NL * NHC];
  const int tid = threadIdx.x;
  for (int i = tid; i < NL * NHC; i += 256) wS[i] = wtag[i];
  __syncthreads();
  const int w = tid >> 6, l = tid & 63;
  const int r = blockIdx.x * 4 + w;
  const float* hp = hcat + (size_t)r * NHC;
  float acc[NL] = {};
#pragma unroll
  for (int rep = 0; rep < 8; ++rep) {
    float hv = hp[l + rep * 64];
#pragma unroll
    for (int j = 0; j < NL; ++j) acc[j] += hv * wS[j * NHC + l + rep * 64];
  }
#pragma unroll
  for (int j = 0; j < NL; ++j) {
#pragma unroll
    for (int off = 32; off; off >>= 1) acc[j] += __shfl_xor(acc[j], off, 64);
  }
  if (l == 0) {
#pragma unroll
    for (int j = 0; j < NL; ++j) em[(size_t)r * NL + j] = acc[j] + btag[j];
  }
}

// -------------------------------------------------------------- crf_fwd -----
__global__ void crf_fwd(const float* __restrict__ em, const int* __restrict__ mask,
                        const int* __restrict__ labels, const float* __restrict__ start,
                        const float* __restrict__ endt, const float* __restrict__ trans,
                        float* __restrict__ d_loss) {
  __shared__ float emS[NT * NL];
  __shared__ float maskS[NT];
  __shared__ int lblS[NT];
  const int b = blockIdx.x;
  const int tid = threadIdx.x;
  for (int i = tid; i < NT * NL; i += 64) emS[i] = em[(size_t)b * NT * NL + i];
  for (int i = tid; i < NT; i += 64) {
    maskS[i] = (float)mask[b * NT + i];
    int lb = labels[b * NT + i];
    lblS[i] = (lb == -100) ? 0 : lb;
  }
  __syncthreads();

  float part = 0.f, msum = 0.f;
  for (int t = tid; t < NT; t += 64) {
    msum += maskS[t];
    if (t >= 1)
      part += (trans[lblS[t - 1] * NL + lblS[t]] + emS[t * NL + lblS[t]]) * maskS[t];
  }
#pragma unroll
  for (int off = 32; off; off >>= 1) {
    part += __shfl_xor(part, off, 64);
    msum += __shfl_xor(msum, off, 64);
  }

  const int j = tid >> 2, q = tid & 3;
  const bool leader = (q == 0) && (j < NL);
  float tr0 = 0.f, tr1 = 0.f, tr2 = -1e30f;
  float score = 0.f;
  if (tid < 36) {
    tr0 = trans[q * NL + j];
    tr1 = trans[(q + 4) * NL + j];
    if (q == 0) tr2 = trans[8 * NL + j];
    if (leader) score = start[j] + emS[j];
  }
  for (int t = 1; t < NT; ++t) {
    float s0 = __shfl(score, q * 4, 64);
    float s1 = __shfl(score, (q + 4) * 4, 64);
    float s2 = __shfl(score, 32, 64);
    float v0 = s0 + tr0, v1 = s1 + tr1;
    float v2 = (q == 0) ? (s2 + tr2) : -1e30f;
    float m = fmaxf(fmaxf(v0, v1), v2);
    m = fmaxf(m, __shfl_xor(m, 1, 4));
    m = fmaxf(m, __shfl_xor(m, 2, 4));
    float e = expf(v0 - m) + expf(v1 - m) + ((q == 0) ? expf(v2 - m) : 0.f);
    e += __shfl_xor(e, 1, 4);
    e += __shfl_xor(e, 2, 4);
    if (leader) {
      float nxt = m + logf(e) + emS[t * NL + j];
      score = (maskS[t] > 0.f) ? nxt : score;
    }
  }
  float vs[NL];
  float mx = -1e30f;
#pragma unroll
  for (int jj = 0; jj < NL; ++jj) {
    float sj = __shfl(score, jj * 4, 64) + endt[jj];
    vs[jj] = sj;
    mx = fmaxf(mx, sj);
  }
  float se = 0.f;
#pragma unroll
  for (int jj = 0; jj < NL; ++jj) se += expf(vs[jj] - mx);
  float denom = mx + logf(se);
  if (tid == 0) {
    int li = (int)(msum - 0.5f);
    float num = start[lblS[0]] + emS[lblS[0]] + part + endt[lblS[li]];
    atomicAdd(d_loss, -(num - denom) * (1.f / 32.f));
  }
}

// ---------------------------------------------------------- crf_viterbi -----
__global__ void crf_viterbi(const float* __restrict__ em, const int* __restrict__ mask,
                            const float* __restrict__ start, const float* __restrict__ endt,
                            const float* __restrict__ trans, float* __restrict__ preds) {
  __shared__ float emS[NT * NL];
  __shared__ int maskS[NT];
  __shared__ short bpS[(NT - 1) * NL];
  __shared__ short tagS[NT];
  const int b = blockIdx.x;
  const int tid = threadIdx.x;
  for (int i = tid; i < NT * NL; i += 64) emS[i] = em[(size_t)b * NT * NL + i];
  for (int i = tid; i < NT; i += 64) maskS[i] = mask[b * NT + i];
  __syncthreads();

  const int j = tid >> 2, q = tid & 3;
  const bool leader = (q == 0) && (j < NL);
  float tr0 = 0.f, tr1 = 0.f, tr2 = -1e30f;
  float score = 0.f;
  if (tid < 36) {
    tr0 = trans[q * NL + j];
    tr1 = trans[(q + 4) * NL + j];
    if (q == 0) tr2 = trans[8 * NL + j];
    if (leader) score = start[j] + emS[j];
  }
  for (int t = 1; t < NT; ++t) {
    float s0 = __shfl(score, q * 4, 64);
    float s1 = __shfl(score, (q + 4) * 4, 64);
    float s2 = __shfl(score, 32, 64);
    float v0 = s0 + tr0, v1 = s1 + tr1;
    float v2 = (q == 0) ? (s2 + tr2) : -1e30f;
    float bv = v0;
    int bi = q;
    if (v1 > bv) { bv = v1; bi = q + 4; }
    if (q == 0 && v2 > bv) { bv = v2; bi = 8; }
#pragma unroll
    for (int off = 1; off <= 2; off <<= 1) {
      float ov = __shfl_xor(bv, off, 4);
      int oi = __shfl_xor(bi, off, 4);
      if (ov > bv || (ov == bv && oi < bi)) { bv = ov; bi = oi; }
    }
    if (leader) {
      int keep = maskS[t];
      float nxt = bv + emS[t * NL + j];
      bpS[(t - 1) * NL + j] = keep ? (short)bi : (short)j;
      score = keep ? nxt : score;
    }
  }
  float fv[NL];
#pragma unroll
  for (int jj = 0; jj < NL; ++jj) fv[jj] = __shfl(score, jj * 4, 64) + endt[jj];
  if (tid == 0) {
    int last = 0;
    float bvv = fv[0];
#pragma unroll
    for (int jj = 1; jj < NL; ++jj)
      if (fv[jj] > bvv) { bvv = fv[jj]; last = jj; }
    tagS[NT - 1] = (short)last;
    for (int t = NT - 1; t >= 1; --t) tagS[t - 1] = bpS[(t - 1) * NL + tagS[t]];
  }
  __syncthreads();
  for (int i = tid; i < NT; i += 64) preds[(size_t)b * NT + i] = (float)tagS[i];
}

// ---------------------------------------------------------------------------
extern "C" void kernel_launch(void* const* d_in, const int* in_sizes, int n_in,
                              void* d_out, int out_size, void* d_ws, size_t ws_size,
                              hipStream_t stream) {
  const float* seq_out = (const float*)d_in[0];
  const int* attn = (const int*)d_in[1];
  const int* labels = (const int*)d_in[2];
  const float* w_ih_f = (const float*)d_in[3];
  const float* w_hh_f = (const float*)d_in[4];
  const float* b_f = (const float*)d_in[5];
  const float* w_ih_b = (const float*)d_in[6];
  const float* w_hh_b = (const float*)d_in[7];
  const float* b_b = (const float*)d_in[8];
  const float* w_tag = (const float*)d_in[9];
  const float* b_tag = (const float*)d_in[10];
  const float* start_t = (const float*)d_in[11];
  const float* end_t = (const float*)d_in[12];
  const float* trans = (const float*)d_in[13];
  (void)in_sizes; (void)n_in; (void)out_size; (void)ws_size;

  float* ws = (float*)d_ws;
  float* w_ihT = ws + OFF_WIHT;
  float* w_hhT = ws + OFF_WHHT;
  float* xpart = ws + OFF_XPART;
  float* hcat = ws + OFF_HCAT;
  float* hG = ws + OFF_HG;
  int* flags = (int*)(ws + OFF_CTR);

  float* em = (float*)d_out;
  float* d_loss = em + NB * NT * NL;
  float* preds = d_loss + 1;

  prep<<<8192, 256, 0, stream>>>(w_ih_f, w_ih_b, w_hh_f, w_hh_b, w_ihT, w_hhT, d_loss, flags);
  gemm_x<<<dim3(16, 128), 256, 0, stream>>>(seq_out, w_ihT, b_f, b_b, xpart);
  lstm_scan<<<32, 512, 0, stream>>>(w_hhT, xpart, hcat, hG, flags);
  emissions<<<4096, 256, 0, stream>>>(hcat, w_tag, b_tag, em);
  crf_fwd<<<32, 64, 0, stream>>>(em, attn, labels, start_t, end_t, trans, d_loss);
  crf_viterbi<<<32, 64, 0, stream>>>(em, attn, start_t, end_t, trans, preds);
}